// Round 10
// baseline (187.427 us; speedup 1.0000x reference)
//
#include <hip/hip_runtime.h>
#include <math.h>

#define FDIM 256
#define NH 8
#define HD 32
#define NQ 4096
#define NKEY 4096
#define CAP 512
#define R2 9.0f

// spatial cells for query pairing
#define NCELL 6
#define NC3   216
#define CCAP  64
#define GBLK  (NC3 * 32)   // 32 pair-slots per cell
#define OCAP  512
#define OBLK  32

typedef _Float16 half8 __attribute__((ext_vector_type(8)));
typedef _Float16 half4v __attribute__((ext_vector_type(4)));
typedef float f32x4 __attribute__((ext_vector_type(4)));
typedef unsigned short ushort_t;

// castbuf layout (f16 elements)
#define CB_CUR  0
#define CB_HIST 1048576
#define CB_WQ   2097152
#define CB_WK   2162688
#define CB_WV   2228224
#define CB_WO   2293760
#define CB_F4_TOTAL 589824

// ---------------------------------------------------------------------------
// prep: [0,1024) neighbor lists (exact fp32 op order); [1024,2048) f32->f16
// cast; [2048,2064) query->cell bucketing (ccnt/ocnt zeroed by memsetAsync).
// ---------------------------------------------------------------------------
__global__ __launch_bounds__(256) void prep(const float* __restrict__ cur,
                                            const float* __restrict__ hist,
                                            const float* __restrict__ Wq,
                                            const float* __restrict__ Wk,
                                            const float* __restrict__ Wv,
                                            const float* __restrict__ Wo,
                                            _Float16* __restrict__ dst,
                                            const float* __restrict__ qc,
                                            const float* __restrict__ kc,
                                            ushort_t* __restrict__ nbr,
                                            int* __restrict__ cnt,
                                            int* __restrict__ ccnt,
                                            int* __restrict__ cellq,
                                            int* __restrict__ ocnt,
                                            int* __restrict__ oq) {
    if (blockIdx.x < 1024) {
        const int q    = blockIdx.x * 4 + (threadIdx.x >> 6);
        const int lane = threadIdx.x & 63;
        const float qx = qc[q * 3 + 0];
        const float qy = qc[q * 3 + 1];
        const float qz = qc[q * 3 + 2];
        int base = 0;
        for (int k0 = 0; k0 < NKEY; k0 += 64) {
            const int k = k0 + lane;
            float dx = __fsub_rn(qx, kc[k * 3 + 0]);
            float dy = __fsub_rn(qy, kc[k * 3 + 1]);
            float dz = __fsub_rn(qz, kc[k * 3 + 2]);
            float d2 = __fadd_rn(__fadd_rn(__fmul_rn(dx, dx), __fmul_rn(dy, dy)),
                                 __fmul_rn(dz, dz));
            bool valid = (d2 <= R2);
            unsigned long long bal = __ballot(valid);
            if (valid) {
                int pos = base + __popcll(bal & ((1ull << lane) - 1ull));
                if (pos < CAP) nbr[(size_t)q * CAP + pos] = (ushort_t)k;
            }
            base += __popcll(bal);
        }
        if (lane == 0) cnt[q] = (base > CAP) ? CAP : base;
    } else if (blockIdx.x < 2048) {
        const int stride = 1024 * 256;
        for (int i4 = (blockIdx.x - 1024) * 256 + threadIdx.x; i4 < CB_F4_TOTAL;
             i4 += stride) {
            const float* src;
            int base;
            if (i4 < 262144)      { src = cur;  base = 0; }
            else if (i4 < 524288) { src = hist; base = 262144; }
            else if (i4 < 540672) { src = Wq;   base = 524288; }
            else if (i4 < 557056) { src = Wk;   base = 540672; }
            else if (i4 < 573440) { src = Wv;   base = 557056; }
            else                  { src = Wo;   base = 573440; }
            float4 v = ((const float4*)src)[i4 - base];
            half4v h;
            h[0] = (_Float16)v.x; h[1] = (_Float16)v.y;
            h[2] = (_Float16)v.z; h[3] = (_Float16)v.w;
            ((half4v*)dst)[i4] = h;
        }
    } else {
        const int q = (blockIdx.x - 2048) * 256 + threadIdx.x;
        const float s = (float)NCELL / 16.0f;
        int ix = (int)(qc[q * 3 + 0] * s);
        int iy = (int)(qc[q * 3 + 1] * s);
        int iz = (int)(qc[q * 3 + 2] * s);
        ix = min(NCELL - 1, max(0, ix));
        iy = min(NCELL - 1, max(0, iy));
        iz = min(NCELL - 1, max(0, iz));
        const int cell = (iz * NCELL + iy) * NCELL + ix;
        const int slot = atomicAdd(&ccnt[cell], 1);
        if (slot < CCAP) cellq[cell * CCAP + slot] = q;
        else { int o = atomicAdd(ocnt, 1); if (o < OCAP) oq[o] = q; }
    }
}

// ---------------------------------------------------------------------------
// MFMA GEMM core (proven shape).
// ---------------------------------------------------------------------------
__device__ __forceinline__ void mfma_tile_16x64(const _Float16* __restrict__ A,
                                                const _Float16* __restrict__ W,
                                                int m0, int n0, int wave, int lane,
                                                f32x4 acc[4]) {
    const int row  = lane & 15;
    const int quad = lane >> 4;
    const _Float16* aptr = A + (size_t)(m0 + wave * 16 + row) * 256 + quad * 8;
    const _Float16* wptr = W + (size_t)(n0 + row) * 256 + quad * 8;
#pragma unroll
    for (int i = 0; i < 4; ++i) acc[i] = (f32x4){0.f, 0.f, 0.f, 0.f};
#pragma unroll
    for (int k0 = 0; k0 < 8; ++k0) {
        half8 a = *(const half8*)(aptr + k0 * 32);
#pragma unroll
        for (int nt = 0; nt < 4; ++nt) {
            half8 b = *(const half8*)(wptr + (size_t)nt * 16 * 256 + k0 * 32);
            acc[nt] = __builtin_amdgcn_mfma_f32_16x16x32_f16(a, b, acc[nt], 0, 0, 0);
        }
    }
}

__global__ __launch_bounds__(256) void qkv_mfma(const _Float16* __restrict__ cb,
                                                const float* __restrict__ bq,
                                                const float* __restrict__ bk,
                                                const float* __restrict__ bv,
                                                _Float16* __restrict__ Qh,
                                                _Float16* __restrict__ KV) {
    const int z    = blockIdx.z;
    const int wave = threadIdx.x >> 6;
    const int lane = threadIdx.x & 63;
    const int m0   = blockIdx.y * 64;
    const int n0   = blockIdx.x * 64;

    const _Float16* A = (z == 0) ? (cb + CB_CUR) : (cb + CB_HIST);
    const _Float16* W = (z == 0) ? (cb + CB_WQ) : (z == 1) ? (cb + CB_WK) : (cb + CB_WV);
    const float* bias = (z == 0) ? bq : (z == 1) ? bk : bv;

    f32x4 acc[4];
    mfma_tile_16x64(A, W, m0, n0, wave, lane, acc);

    const int col  = lane & 15;
    const int quad = lane >> 4;
    float bs[4];
#pragma unroll
    for (int nt = 0; nt < 4; ++nt) bs[nt] = bias[n0 + nt * 16 + col];

    if (z == 0) {
#pragma unroll
        for (int nt = 0; nt < 4; ++nt)
#pragma unroll
            for (int r = 0; r < 4; ++r)
                Qh[(size_t)(m0 + wave * 16 + quad * 4 + r) * 256 + n0 + nt * 16 + col] =
                    (_Float16)(acc[nt][r] + bs[nt]);
    } else {
        const int off = (z == 1) ? 0 : 256;
#pragma unroll
        for (int nt = 0; nt < 4; ++nt)
#pragma unroll
            for (int r = 0; r < 4; ++r)
                KV[(size_t)(m0 + wave * 16 + quad * 4 + r) * 512 + off + n0 + nt * 16 + col] =
                    (_Float16)(acc[nt][r] + bs[nt]);
    }
}

__global__ __launch_bounds__(256) void o_mfma(const _Float16* __restrict__ Ob,
                                              const _Float16* __restrict__ Wo,
                                              const float* __restrict__ bo,
                                              float* __restrict__ out) {
    const int wave = threadIdx.x >> 6;
    const int lane = threadIdx.x & 63;
    const int m0   = blockIdx.y * 64;
    const int n0   = blockIdx.x * 64;

    f32x4 acc[4];
    mfma_tile_16x64(Ob, Wo, m0, n0, wave, lane, acc);

    const int col  = lane & 15;
    const int quad = lane >> 4;
#pragma unroll
    for (int nt = 0; nt < 4; ++nt) {
        const float b = bo[n0 + nt * 16 + col];
#pragma unroll
        for (int r = 0; r < 4; ++r)
            out[(size_t)(m0 + wave * 16 + quad * 4 + r) * 256 + n0 + nt * 16 + col] =
                acc[nt][r] + b;
    }
}

// ---------------------------------------------------------------------------
// Paired sparse attention v10. One block serves a PAIR of same-cell queries.
// Neighbor lists are sorted (built in ascending k), so the union with 2-bit
// membership masks is built by binary-search merge in LDS (~4 KB, vs R8's
// 31 KB bitmaps). Main loop = attn9's exp-free accumulation, but ONE KV
// fetch feeds BOTH queries (overlap ~65% -> ~0.67x L2 traffic).
// lane = p*32 + hs (hs = h*4+s, dims [hs*8, hs*8+8)); 8 streams via
// (wave, p); per-key score restored by shfl_xor(1)+shfl_xor(2).
// ---------------------------------------------------------------------------
__device__ __forceinline__ int lb16(const ushort_t* a, int n, int key) {
    int lo = 0, hi = n;
    while (lo < hi) { int mid = (lo + hi) >> 1; if (a[mid] < key) lo = mid + 1; else hi = mid; }
    return lo;
}

__device__ __forceinline__ void process_pair(
        int q0, int q1, int nq,
        const _Float16* __restrict__ Qh, const _Float16* __restrict__ KV,
        const ushort_t* __restrict__ nbr, const int* __restrict__ cnt,
        _Float16* __restrict__ Ob,
        ushort_t* sl0, ushort_t* sl1, unsigned int* ulist, int* ucnt,
        float (*sm)[32][18]) {
    const int t    = threadIdx.x;
    const int wave = t >> 6;
    const int lane = t & 63;
    const int p    = lane >> 5;
    const int hs   = lane & 31;

    const int n0 = cnt[q0];
    const int n1 = (nq == 2) ? cnt[q1] : 0;

    // stage sorted lists into LDS
    for (int i = t; i < n0; i += 256) sl0[i] = nbr[(size_t)q0 * CAP + i];
    for (int i = t; i < n1; i += 256) sl1[i] = nbr[(size_t)q1 * CAP + i];
    if (t == 0) *ucnt = 0;
    __syncthreads();

    // union with 2-bit membership masks
    for (int i = t; i < n0; i += 256) {
        const int key = sl0[i];
        const int j   = lb16(sl1, n1, key);
        const int f1  = (j < n1 && sl1[j] == key) ? 1 : 0;
        ulist[atomicAdd(ucnt, 1)] = (unsigned int)key | (1u << 16) | ((unsigned int)f1 << 17);
    }
    for (int i = t; i < n1; i += 256) {
        const int key = sl1[i];
        const int j   = lb16(sl0, n0, key);
        if (!(j < n0 && sl0[j] == key))
            ulist[atomicAdd(ucnt, 1)] = (unsigned int)key | (2u << 16);
    }
    __syncthreads();
    const int U = *ucnt;

    // q fragments, pre-scaled
    float qv0[8], qv1[8];
    {
        const float sc = 0.17677669529663687f;
        half8 a = *(const half8*)(Qh + (size_t)q0 * FDIM + hs * 8);
        half8 b = *(const half8*)(Qh + (size_t)q1 * FDIM + hs * 8);
#pragma unroll
        for (int i = 0; i < 8; ++i) { qv0[i] = (float)a[i] * sc; qv1[i] = (float)b[i] * sc; }
    }

    float o0[8], o1[8];
#pragma unroll
    for (int i = 0; i < 8; ++i) { o0[i] = 0.f; o1[i] = 0.f; }
    float l0 = 0.f, l1 = 0.f;

    const int koff = hs * 8;
    for (int j = 2 * wave + p; j < U; j += 8) {
        const unsigned int e = ulist[j];
        const int k = e & 0xFFFF;
        const _Float16* r = KV + ((size_t)k << 9) + koff;
        half8 k8 = *(const half8*)(r);
        half8 v8 = *(const half8*)(r + 256);

        float d0 = 0.f, d1 = 0.f;
#pragma unroll
        for (int i = 0; i < 8; ++i) {
            const float kf = (float)k8[i];
            d0 = fmaf(qv0[i], kf, d0);
            d1 = fmaf(qv1[i], kf, d1);
        }
        d0 += __shfl_xor(d0, 1, 64); d0 += __shfl_xor(d0, 2, 64);
        d1 += __shfl_xor(d1, 1, 64); d1 += __shfl_xor(d1, 2, 64);

        const float pw0 = (e & (1u << 16)) ? __expf(d0) : 0.f;
        const float pw1 = (e & (1u << 17)) ? __expf(d1) : 0.f;
        l0 += pw0; l1 += pw1;
#pragma unroll
        for (int i = 0; i < 8; ++i) {
            const float vf = (float)v8[i];
            o0[i] = fmaf(pw0, vf, o0[i]);
            o1[i] = fmaf(pw1, vf, o1[i]);
        }
    }

    // plain-sum merges: halves, then waves via LDS
    l0 += __shfl_xor(l0, 32, 64);
    l1 += __shfl_xor(l1, 32, 64);
#pragma unroll
    for (int i = 0; i < 8; ++i) {
        o0[i] += __shfl_xor(o0[i], 32, 64);
        o1[i] += __shfl_xor(o1[i], 32, 64);
    }

    if (lane < 32) {
        float* d = &sm[wave][lane][0];
        *(float4*)(d)      = (float4){o0[0], o0[1], o0[2], o0[3]};
        *(float4*)(d + 4)  = (float4){o0[4], o0[5], o0[6], o0[7]};
        d[8] = l0;
        *(float4*)(d + 9)  = (float4){o1[0], o1[1], o1[2], o1[3]};
        *(float4*)(d + 13) = (float4){o1[4], o1[5], o1[6], o1[7]};
        d[17] = l1;
    }
    __syncthreads();

    if (t < 32) {
        float O0[8], O1[8], L0, L1;
        {
            const float* d = &sm[0][t][0];
#pragma unroll
            for (int i = 0; i < 8; ++i) { O0[i] = d[i]; O1[i] = d[9 + i]; }
            L0 = d[8]; L1 = d[17];
        }
#pragma unroll
        for (int w = 1; w < 4; ++w) {
            const float* d = &sm[w][t][0];
#pragma unroll
            for (int i = 0; i < 8; ++i) { O0[i] += d[i]; O1[i] += d[9 + i]; }
            L0 += d[8]; L1 += d[17];
        }
        const float inv0 = 1.0f / L0;
        half8 h0;
#pragma unroll
        for (int i = 0; i < 8; ++i) h0[i] = (_Float16)(O0[i] * inv0);
        *(half8*)(Ob + (size_t)q0 * FDIM + t * 8) = h0;
        if (nq == 2) {
            const float inv1 = 1.0f / L1;
            half8 h1;
#pragma unroll
            for (int i = 0; i < 8; ++i) h1[i] = (_Float16)(O1[i] * inv1);
            *(half8*)(Ob + (size_t)q1 * FDIM + t * 8) = h1;
        }
    }
    __syncthreads();  // LDS reuse safety for looped callers
}

__global__ __launch_bounds__(256) void sparse_attn10(
        const _Float16* __restrict__ Qh, const _Float16* __restrict__ KV,
        const ushort_t* __restrict__ nbr, const int* __restrict__ cnt,
        const int* __restrict__ ccnt, const int* __restrict__ cellq,
        const int* __restrict__ ocnt, const int* __restrict__ oq,
        _Float16* __restrict__ Ob) {
    __shared__ ushort_t sl0[CAP], sl1[CAP];
    __shared__ unsigned int ulist[2 * CAP];
    __shared__ int ucnt;
    __shared__ float sm[4][32][18];

    if (blockIdx.x < GBLK) {
        const int c  = blockIdx.x >> 5;
        const int i  = blockIdx.x & 31;
        const int cc = min(ccnt[c], CCAP);
        if (2 * i >= cc) return;
        const int q0 = cellq[c * CCAP + 2 * i];
        const int nq = (2 * i + 1 < cc) ? 2 : 1;
        const int q1 = (nq == 2) ? cellq[c * CCAP + 2 * i + 1] : q0;
        process_pair(q0, q1, nq, Qh, KV, nbr, cnt, Ob, sl0, sl1, ulist, &ucnt, sm);
    } else {
        const int oc = min(*ocnt, OCAP);
        for (int i = blockIdx.x - GBLK; i < oc; i += OBLK) {
            const int qq = oq[i];
            process_pair(qq, qq, 1, Qh, KV, nbr, cnt, Ob, sl0, sl1, ulist, &ucnt, sm);
        }
    }
}

// ---------------------------------------------------------------------------
extern "C" void kernel_launch(void* const* d_in, const int* in_sizes, int n_in,
                              void* d_out, int out_size, void* d_ws, size_t ws_size,
                              hipStream_t stream) {
    const float* cur_feats   = (const float*)d_in[0];
    const float* hist_feats  = (const float*)d_in[1];
    const float* cur_coords  = (const float*)d_in[2];
    const float* hist_coords = (const float*)d_in[3];
    const float* bq = (const float*)d_in[5];
    const float* bk = (const float*)d_in[7];
    const float* bv = (const float*)d_in[9];
    const float* bo = (const float*)d_in[11];
    float* out = (float*)d_out;

    char* w = (char*)d_ws;
    _Float16*  Qh   = (_Float16*)(w);                      // 2 MiB
    _Float16*  KV   = (_Float16*)(w + (4 << 20));          // 4 MiB
    ushort_t*  nbr  = (ushort_t*)(w + (8 << 20));          // 4 MiB
    int*       cnt  = (int*)(w + (12 << 20));              // 16 KiB
    _Float16*  Ob   = (_Float16*)(w + (12 << 20) + (64 << 10));  // 2 MiB
    _Float16*  cb   = (_Float16*)(w + (15 << 20));         // ~4.5 MiB
    int*       ccnt = (int*)(w + (20 << 20));              // 216 + 1 ints
    int*       ocnt = ccnt + NC3;
    int*       cellq= (int*)(w + (20 << 20) + 1024);       // 216*64 ints
    int*       oq   = (int*)(w + (20 << 20) + 1024 + NC3 * CCAP * 4);

    hipMemsetAsync(ccnt, 0, (NC3 + 1) * sizeof(int), stream);

    prep<<<2064, 256, 0, stream>>>(cur_feats, hist_feats,
                                   (const float*)d_in[4], (const float*)d_in[6],
                                   (const float*)d_in[8], (const float*)d_in[10], cb,
                                   cur_coords, hist_coords, nbr, cnt,
                                   ccnt, cellq, ocnt, oq);

    qkv_mfma<<<dim3(4, 64, 3), 256, 0, stream>>>(cb, bq, bk, bv, Qh, KV);

    sparse_attn10<<<GBLK + OBLK, 256, 0, stream>>>(Qh, KV, nbr, cnt,
                                                   ccnt, cellq, ocnt, oq, Ob);

    o_mfma<<<dim3(4, 64), 256, 0, stream>>>(Ob, cb + CB_WO, bo, out);
}

// Round 12
// 148.029 us; speedup vs baseline: 1.2662x; 1.2662x over previous
//
#include <hip/hip_runtime.h>
#include <math.h>

#define FDIM 256
#define NH 8
#define HD 32
#define NQ 4096
#define NKEY 4096
#define CAP 512
#define R2 9.0f

typedef _Float16 half8 __attribute__((ext_vector_type(8)));
typedef _Float16 half4v __attribute__((ext_vector_type(4)));
typedef float f32x4 __attribute__((ext_vector_type(4)));
typedef unsigned short ushort_t;

// weight cast buffer (f16 elements)
#define CBW_WQ 0
#define CBW_WK 65536
#define CBW_WV 131072
#define CBW_WO 196608
#define CBW_F4 65536   // 4 * 65536 floats / 4

// ---------------------------------------------------------------------------
// prep2: [0,1024) neighbor lists (exact reference fp32 op order, no
// contraction); [1024,1088) f32->f16 cast of the 4 weight matrices (512 KB).
// The 12 MB cur/hist cast is gone: qkv_mfma2 converts in-register.
// ---------------------------------------------------------------------------
__global__ __launch_bounds__(256) void prep2(const float* __restrict__ Wq,
                                             const float* __restrict__ Wk,
                                             const float* __restrict__ Wv,
                                             const float* __restrict__ Wo,
                                             _Float16* __restrict__ cbw,
                                             const float* __restrict__ qc,
                                             const float* __restrict__ kc,
                                             ushort_t* __restrict__ nbr,
                                             int* __restrict__ cnt) {
    if (blockIdx.x < 1024) {
        const int q    = blockIdx.x * 4 + (threadIdx.x >> 6);
        const int lane = threadIdx.x & 63;
        const float qx = qc[q * 3 + 0];
        const float qy = qc[q * 3 + 1];
        const float qz = qc[q * 3 + 2];
        int base = 0;
        for (int k0 = 0; k0 < NKEY; k0 += 64) {
            const int k = k0 + lane;
            float dx = __fsub_rn(qx, kc[k * 3 + 0]);
            float dy = __fsub_rn(qy, kc[k * 3 + 1]);
            float dz = __fsub_rn(qz, kc[k * 3 + 2]);
            float d2 = __fadd_rn(__fadd_rn(__fmul_rn(dx, dx), __fmul_rn(dy, dy)),
                                 __fmul_rn(dz, dz));
            bool valid = (d2 <= R2);
            unsigned long long bal = __ballot(valid);
            if (valid) {
                int pos = base + __popcll(bal & ((1ull << lane) - 1ull));
                if (pos < CAP) nbr[(size_t)q * CAP + pos] = (ushort_t)k;
            }
            base += __popcll(bal);
        }
        if (lane == 0) cnt[q] = (base > CAP) ? CAP : base;
    } else {
        const int stride = 64 * 256;
        for (int i4 = (blockIdx.x - 1024) * 256 + threadIdx.x; i4 < CBW_F4;
             i4 += stride) {
            const float* src;
            int base;
            if (i4 < 16384)      { src = Wq; base = 0; }
            else if (i4 < 32768) { src = Wk; base = 16384; }
            else if (i4 < 49152) { src = Wv; base = 32768; }
            else                 { src = Wo; base = 49152; }
            float4 v = ((const float4*)src)[i4 - base];
            half4v h;
            h[0] = (_Float16)v.x; h[1] = (_Float16)v.y;
            h[2] = (_Float16)v.z; h[3] = (_Float16)v.w;
            ((half4v*)cbw)[i4] = h;
        }
    }
}

// ---------------------------------------------------------------------------
// MFMA GEMM cores (proven wave tile 16x64, no LDS).
// A-frag A[m=lane&15][k=quad*8+j]; B-frag = 8 contiguous f16 of a W row.
// C/D: row=quad*4+r, col=lane&15.
// Variant 1: A in fp32, converted in-register (bit-identical to cast-first).
// ---------------------------------------------------------------------------
__device__ __forceinline__ void mfma_tile_16x64_af32(const float* __restrict__ A,
                                                     const _Float16* __restrict__ W,
                                                     int m0, int n0, int wave, int lane,
                                                     f32x4 acc[4]) {
    const int row  = lane & 15;
    const int quad = lane >> 4;
    const float*    aptr = A + (size_t)(m0 + wave * 16 + row) * 256 + quad * 8;
    const _Float16* wptr = W + (size_t)(n0 + row) * 256 + quad * 8;
#pragma unroll
    for (int i = 0; i < 4; ++i) acc[i] = (f32x4){0.f, 0.f, 0.f, 0.f};
#pragma unroll
    for (int k0 = 0; k0 < 8; ++k0) {
        float4 a0 = *(const float4*)(aptr + k0 * 32);
        float4 a1 = *(const float4*)(aptr + k0 * 32 + 4);
        half8 a;
        a[0] = (_Float16)a0.x; a[1] = (_Float16)a0.y;
        a[2] = (_Float16)a0.z; a[3] = (_Float16)a0.w;
        a[4] = (_Float16)a1.x; a[5] = (_Float16)a1.y;
        a[6] = (_Float16)a1.z; a[7] = (_Float16)a1.w;
#pragma unroll
        for (int nt = 0; nt < 4; ++nt) {
            half8 b = *(const half8*)(wptr + (size_t)nt * 16 * 256 + k0 * 32);
            acc[nt] = __builtin_amdgcn_mfma_f32_16x16x32_f16(a, b, acc[nt], 0, 0, 0);
        }
    }
}

// Variant 2: A already f16 (used by o_mfma on Ob).
__device__ __forceinline__ void mfma_tile_16x64(const _Float16* __restrict__ A,
                                                const _Float16* __restrict__ W,
                                                int m0, int n0, int wave, int lane,
                                                f32x4 acc[4]) {
    const int row  = lane & 15;
    const int quad = lane >> 4;
    const _Float16* aptr = A + (size_t)(m0 + wave * 16 + row) * 256 + quad * 8;
    const _Float16* wptr = W + (size_t)(n0 + row) * 256 + quad * 8;
#pragma unroll
    for (int i = 0; i < 4; ++i) acc[i] = (f32x4){0.f, 0.f, 0.f, 0.f};
#pragma unroll
    for (int k0 = 0; k0 < 8; ++k0) {
        half8 a = *(const half8*)(aptr + k0 * 32);
#pragma unroll
        for (int nt = 0; nt < 4; ++nt) {
            half8 b = *(const half8*)(wptr + (size_t)nt * 16 * 256 + k0 * 32);
            acc[nt] = __builtin_amdgcn_mfma_f32_16x16x32_f16(a, b, acc[nt], 0, 0, 0);
        }
    }
}

// Fused QKV. z=0: Q f16 out (row-major). z=1/2: K/V f16 into row-major
// interleaved KV[k][0:256]=K, KV[k][256:512]=V. A read as fp32 directly.
__global__ __launch_bounds__(256) void qkv_mfma2(const float* __restrict__ cur,
                                                 const float* __restrict__ hist,
                                                 const _Float16* __restrict__ cbw,
                                                 const float* __restrict__ bq,
                                                 const float* __restrict__ bk,
                                                 const float* __restrict__ bv,
                                                 _Float16* __restrict__ Qh,
                                                 _Float16* __restrict__ KV) {
    const int z    = blockIdx.z;
    const int wave = threadIdx.x >> 6;
    const int lane = threadIdx.x & 63;
    const int m0   = blockIdx.y * 64;
    const int n0   = blockIdx.x * 64;

    const float* A = (z == 0) ? cur : hist;
    const _Float16* W = cbw + ((z == 0) ? CBW_WQ : (z == 1) ? CBW_WK : CBW_WV);
    const float* bias = (z == 0) ? bq : (z == 1) ? bk : bv;

    f32x4 acc[4];
    mfma_tile_16x64_af32(A, W, m0, n0, wave, lane, acc);

    const int col  = lane & 15;
    const int quad = lane >> 4;
    float bs[4];
#pragma unroll
    for (int nt = 0; nt < 4; ++nt) bs[nt] = bias[n0 + nt * 16 + col];

    if (z == 0) {
#pragma unroll
        for (int nt = 0; nt < 4; ++nt)
#pragma unroll
            for (int r = 0; r < 4; ++r)
                Qh[(size_t)(m0 + wave * 16 + quad * 4 + r) * 256 + n0 + nt * 16 + col] =
                    (_Float16)(acc[nt][r] + bs[nt]);
    } else {
        const int off = (z == 1) ? 0 : 256;
#pragma unroll
        for (int nt = 0; nt < 4; ++nt)
#pragma unroll
            for (int r = 0; r < 4; ++r)
                KV[(size_t)(m0 + wave * 16 + quad * 4 + r) * 512 + off + n0 + nt * 16 + col] =
                    (_Float16)(acc[nt][r] + bs[nt]);
    }
}

// O-projection: out fp32 = Ob_f16 * Wo_f16^T + bo
__global__ __launch_bounds__(256) void o_mfma(const _Float16* __restrict__ Ob,
                                              const _Float16* __restrict__ Wo,
                                              const float* __restrict__ bo,
                                              float* __restrict__ out) {
    const int wave = threadIdx.x >> 6;
    const int lane = threadIdx.x & 63;
    const int m0   = blockIdx.y * 64;
    const int n0   = blockIdx.x * 64;

    f32x4 acc[4];
    mfma_tile_16x64(Ob, Wo, m0, n0, wave, lane, acc);

    const int col  = lane & 15;
    const int quad = lane >> 4;
#pragma unroll
    for (int nt = 0; nt < 4; ++nt) {
        const float b = bo[n0 + nt * 16 + col];
#pragma unroll
        for (int r = 0; r < 4; ++r)
            out[(size_t)(m0 + wave * 16 + quad * 4 + r) * 256 + n0 + nt * 16 + col] =
                acc[nt][r] + b;
    }
}

// ---------------------------------------------------------------------------
// Sparse attention v12 = proven v9 loop (exp-free accumulation: scores are
// O(1), softmax is shift-invariant, so l += e^s, o += e^s*v with no
// max-chain), processing TWO queries per block (q, q+2048) to halve
// launch/prologue overhead share and shorten the drain tail.
// lane = p*32 + h*4 + s; 8 half-wave-coalesced neighbor streams per query;
// score restored across the 4 s-lanes via shfl_xor(1)+shfl_xor(2).
// ---------------------------------------------------------------------------
__global__ __launch_bounds__(256) void sparse_attn12(const _Float16* __restrict__ Qh,
                                                     const _Float16* __restrict__ KV,
                                                     const ushort_t* __restrict__ nbr,
                                                     const int* __restrict__ cnt,
                                                     _Float16* __restrict__ Ob) {
    __shared__ float sm[4][32][12];
    const int t    = threadIdx.x;
    const int wave = t >> 6;
    const int lane = t & 63;
    const int p    = lane >> 5;
    const int h    = (lane >> 2) & 7;
    const int s    = lane & 3;
    const int koff = h * HD + s * 8;

    for (int qi = 0; qi < 2; ++qi) {
        const int q = blockIdx.x + qi * 2048;

        // 8-dim q slice for (h,s), f16 -> fp32, pre-scaled by 1/sqrt(HD)
        float qv[8];
        {
            half8 qh = *(const half8*)(Qh + (size_t)q * FDIM + koff);
            const float sc = 0.17677669529663687f;
#pragma unroll
            for (int i = 0; i < 8; ++i) qv[i] = (float)qh[i] * sc;
        }

        float o[8];
#pragma unroll
        for (int i = 0; i < 8; ++i) o[i] = 0.f;
        float l = 0.f;

        const int n = cnt[q];
        const ushort_t* nl = nbr + (size_t)q * CAP;

        for (int j = 2 * wave + p; j < n; j += 8) {
            const int k = nl[j];
            const _Float16* r = KV + ((size_t)k << 9) + koff;
            half8 k8 = *(const half8*)(r);
            half8 v8 = *(const half8*)(r + 256);

            float part = 0.f;
#pragma unroll
            for (int i = 0; i < 8; ++i)
                part = fmaf(qv[i], (float)k8[i], part);
            part += __shfl_xor(part, 1, 64);
            part += __shfl_xor(part, 2, 64);

            const float pw = __expf(part);
            l += pw;
#pragma unroll
            for (int i = 0; i < 8; ++i)
                o[i] = fmaf(pw, (float)v8[i], o[i]);
        }

        // plain-sum merges: halves, then waves via LDS
        l += __shfl_xor(l, 32, 64);
#pragma unroll
        for (int i = 0; i < 8; ++i) o[i] += __shfl_xor(o[i], 32, 64);

        if (lane < 32) {  // lane == h*4+s
            float* dst = &sm[wave][lane][0];
            *(float4*)(dst)     = (float4){o[0], o[1], o[2], o[3]};
            *(float4*)(dst + 4) = (float4){o[4], o[5], o[6], o[7]};
            dst[8] = l;
        }
        __syncthreads();

        if (t < 32) {  // t == h*4+s ; output dims [8t, 8t+8)
            float4 x0 = *(const float4*)&sm[0][t][0];
            float4 x1 = *(const float4*)&sm[0][t][4];
            float O[8] = {x0.x, x0.y, x0.z, x0.w, x1.x, x1.y, x1.z, x1.w};
            float L = sm[0][t][8];
#pragma unroll
            for (int w = 1; w < 4; ++w) {
                float4 y0 = *(const float4*)&sm[w][t][0];
                float4 y1 = *(const float4*)&sm[w][t][4];
                L += sm[w][t][8];
                O[0] += y0.x; O[1] += y0.y; O[2] += y0.z; O[3] += y0.w;
                O[4] += y1.x; O[5] += y1.y; O[6] += y1.z; O[7] += y1.w;
            }
            const float inv = 1.0f / L;  // n==0 -> NaN, matches ref
            half8 ho;
#pragma unroll
            for (int i = 0; i < 8; ++i) ho[i] = (_Float16)(O[i] * inv);
            *(half8*)(Ob + (size_t)q * FDIM + t * 8) = ho;
        }
        __syncthreads();  // sm safe to reuse for next query
    }
}

// ---------------------------------------------------------------------------
extern "C" void kernel_launch(void* const* d_in, const int* in_sizes, int n_in,
                              void* d_out, int out_size, void* d_ws, size_t ws_size,
                              hipStream_t stream) {
    const float* cur_feats   = (const float*)d_in[0];
    const float* hist_feats  = (const float*)d_in[1];
    const float* cur_coords  = (const float*)d_in[2];
    const float* hist_coords = (const float*)d_in[3];
    const float* Wq = (const float*)d_in[4];
    const float* bq = (const float*)d_in[5];
    const float* Wk = (const float*)d_in[6];
    const float* bk = (const float*)d_in[7];
    const float* Wv = (const float*)d_in[8];
    const float* bv = (const float*)d_in[9];
    const float* Wo = (const float*)d_in[10];
    const float* bo = (const float*)d_in[11];
    float* out = (float*)d_out;

    char* w = (char*)d_ws;
    _Float16*  Qh   = (_Float16*)(w);                      // 2 MiB
    _Float16*  KV   = (_Float16*)(w + (4 << 20));          // 4 MiB
    ushort_t*  nbr  = (ushort_t*)(w + (8 << 20));          // 4 MiB
    int*       cnt  = (int*)(w + (12 << 20));              // 16 KiB
    _Float16*  Ob   = (_Float16*)(w + (12 << 20) + (64 << 10));  // 2 MiB
    _Float16*  cbw  = (_Float16*)(w + (15 << 20));         // 512 KiB weights f16

    prep2<<<1088, 256, 0, stream>>>(Wq, Wk, Wv, Wo, cbw,
                                    cur_coords, hist_coords, nbr, cnt);

    qkv_mfma2<<<dim3(4, 64, 3), 256, 0, stream>>>(cur_feats, hist_feats, cbw,
                                                  bq, bk, bv, Qh, KV);

    sparse_attn12<<<2048, 256, 0, stream>>>(Qh, KV, nbr, cnt, Ob);

    o_mfma<<<dim3(4, 64), 256, 0, stream>>>(Ob, cbw + CBW_WO, bo, out);
}

// Round 13
// 145.581 us; speedup vs baseline: 1.2874x; 1.0168x over previous
//
#include <hip/hip_runtime.h>
#include <math.h>

#define FDIM 256
#define NH 8
#define HD 32
#define NQ 4096
#define NKEY 4096
#define CAP 512
#define R2 9.0f

typedef _Float16 half8 __attribute__((ext_vector_type(8)));
typedef _Float16 half4v __attribute__((ext_vector_type(4)));
typedef float f32x4 __attribute__((ext_vector_type(4)));
typedef unsigned short ushort_t;

// castbuf layout (f16 elements)
#define CB_CUR  0
#define CB_HIST 1048576
#define CB_WQ   2097152
#define CB_WK   2162688
#define CB_WV   2228224
#define CB_WO   2293760
#define CB_F4_TOTAL 589824  // total float4 groups (2359296 floats / 4)

// ---------------------------------------------------------------------------
// prep: blocks [0,1024) build the neighbor lists; blocks [1024,2048) cast all
// GEMM inputs fp32->fp16 (grid-stride). Fused to save a launch.
// ---------------------------------------------------------------------------
__global__ __launch_bounds__(256) void prep(const float* __restrict__ cur,
                                            const float* __restrict__ hist,
                                            const float* __restrict__ Wq,
                                            const float* __restrict__ Wk,
                                            const float* __restrict__ Wv,
                                            const float* __restrict__ Wo,
                                            _Float16* __restrict__ dst,
                                            const float* __restrict__ qc,
                                            const float* __restrict__ kc,
                                            ushort_t* __restrict__ nbr,
                                            int* __restrict__ cnt) {
    if (blockIdx.x < 1024) {
        // ---- neighbor build: exact reference fp32 op order (no contraction)
        const int q    = blockIdx.x * 4 + (threadIdx.x >> 6);
        const int lane = threadIdx.x & 63;
        const float qx = qc[q * 3 + 0];
        const float qy = qc[q * 3 + 1];
        const float qz = qc[q * 3 + 2];
        int base = 0;
        for (int k0 = 0; k0 < NKEY; k0 += 64) {
            const int k = k0 + lane;
            float dx = __fsub_rn(qx, kc[k * 3 + 0]);
            float dy = __fsub_rn(qy, kc[k * 3 + 1]);
            float dz = __fsub_rn(qz, kc[k * 3 + 2]);
            float d2 = __fadd_rn(__fadd_rn(__fmul_rn(dx, dx), __fmul_rn(dy, dy)),
                                 __fmul_rn(dz, dz));
            bool valid = (d2 <= R2);
            unsigned long long bal = __ballot(valid);
            if (valid) {
                int pos = base + __popcll(bal & ((1ull << lane) - 1ull));
                if (pos < CAP) nbr[(size_t)q * CAP + pos] = (ushort_t)k;
            }
            base += __popcll(bal);
        }
        if (lane == 0) cnt[q] = (base > CAP) ? CAP : base;
    } else {
        // ---- fp32 -> fp16 cast of feats + weights
        const int stride = 1024 * 256;
        for (int i4 = (blockIdx.x - 1024) * 256 + threadIdx.x; i4 < CB_F4_TOTAL;
             i4 += stride) {
            const float* src;
            int base;
            if (i4 < 262144)      { src = cur;  base = 0; }
            else if (i4 < 524288) { src = hist; base = 262144; }
            else if (i4 < 540672) { src = Wq;   base = 524288; }
            else if (i4 < 557056) { src = Wk;   base = 540672; }
            else if (i4 < 573440) { src = Wv;   base = 557056; }
            else                  { src = Wo;   base = 573440; }
            float4 v = ((const float4*)src)[i4 - base];
            half4v h;
            h[0] = (_Float16)v.x; h[1] = (_Float16)v.y;
            h[2] = (_Float16)v.z; h[3] = (_Float16)v.w;
            ((half4v*)dst)[i4] = h;
        }
    }
}

// ---------------------------------------------------------------------------
// MFMA GEMM core: C[m][n] = sum_k A[m][k] * W[n][k]  (f16 row-major, K=256).
// Wave tile 16x64, no LDS. A-frag A[m=lane&15][k=quad*8+j]; B-frag = 8
// contiguous f16 of a W row. C/D: row=quad*4+r, col=lane&15.
// ---------------------------------------------------------------------------
__device__ __forceinline__ void mfma_tile_16x64(const _Float16* __restrict__ A,
                                                const _Float16* __restrict__ W,
                                                int m0, int n0, int wave, int lane,
                                                f32x4 acc[4]) {
    const int row  = lane & 15;
    const int quad = lane >> 4;
    const _Float16* aptr = A + (size_t)(m0 + wave * 16 + row) * 256 + quad * 8;
    const _Float16* wptr = W + (size_t)(n0 + row) * 256 + quad * 8;
#pragma unroll
    for (int i = 0; i < 4; ++i) acc[i] = (f32x4){0.f, 0.f, 0.f, 0.f};
#pragma unroll
    for (int k0 = 0; k0 < 8; ++k0) {
        half8 a = *(const half8*)(aptr + k0 * 32);
#pragma unroll
        for (int nt = 0; nt < 4; ++nt) {
            half8 b = *(const half8*)(wptr + (size_t)nt * 16 * 256 + k0 * 32);
            acc[nt] = __builtin_amdgcn_mfma_f32_16x16x32_f16(a, b, acc[nt], 0, 0, 0);
        }
    }
}

// Fused QKV. z=0: Q f16 out (row-major [q][256]). z=1/2: K/V f16 into
// row-major interleaved KV[k][0:256]=K, KV[k][256:512]=V.
__global__ __launch_bounds__(256) void qkv_mfma(const _Float16* __restrict__ cb,
                                                const float* __restrict__ bq,
                                                const float* __restrict__ bk,
                                                const float* __restrict__ bv,
                                                _Float16* __restrict__ Qh,
                                                _Float16* __restrict__ KV) {
    const int z    = blockIdx.z;
    const int wave = threadIdx.x >> 6;
    const int lane = threadIdx.x & 63;
    const int m0   = blockIdx.y * 64;
    const int n0   = blockIdx.x * 64;

    const _Float16* A = (z == 0) ? (cb + CB_CUR) : (cb + CB_HIST);
    const _Float16* W = (z == 0) ? (cb + CB_WQ) : (z == 1) ? (cb + CB_WK) : (cb + CB_WV);
    const float* bias = (z == 0) ? bq : (z == 1) ? bk : bv;

    f32x4 acc[4];
    mfma_tile_16x64(A, W, m0, n0, wave, lane, acc);

    const int col  = lane & 15;
    const int quad = lane >> 4;
    float bs[4];
#pragma unroll
    for (int nt = 0; nt < 4; ++nt) bs[nt] = bias[n0 + nt * 16 + col];

    if (z == 0) {
#pragma unroll
        for (int nt = 0; nt < 4; ++nt)
#pragma unroll
            for (int r = 0; r < 4; ++r)
                Qh[(size_t)(m0 + wave * 16 + quad * 4 + r) * 256 + n0 + nt * 16 + col] =
                    (_Float16)(acc[nt][r] + bs[nt]);
    } else {
        const int off = (z == 1) ? 0 : 256;
#pragma unroll
        for (int nt = 0; nt < 4; ++nt)
#pragma unroll
            for (int r = 0; r < 4; ++r)
                KV[(size_t)(m0 + wave * 16 + quad * 4 + r) * 512 + off + n0 + nt * 16 + col] =
                    (_Float16)(acc[nt][r] + bs[nt]);
    }
}

// O-projection: out fp32 = Ob_f16 * Wo_f16^T + bo
__global__ __launch_bounds__(256) void o_mfma(const _Float16* __restrict__ Ob,
                                              const _Float16* __restrict__ Wo,
                                              const float* __restrict__ bo,
                                              float* __restrict__ out) {
    const int wave = threadIdx.x >> 6;
    const int lane = threadIdx.x & 63;
    const int m0   = blockIdx.y * 64;
    const int n0   = blockIdx.x * 64;

    f32x4 acc[4];
    mfma_tile_16x64(Ob, Wo, m0, n0, wave, lane, acc);

    const int col  = lane & 15;
    const int quad = lane >> 4;
#pragma unroll
    for (int nt = 0; nt < 4; ++nt) {
        const float b = bo[n0 + nt * 16 + col];
#pragma unroll
        for (int r = 0; r < 4; ++r)
            out[(size_t)(m0 + wave * 16 + quad * 4 + r) * 256 + n0 + nt * 16 + col] =
                acc[nt][r] + b;
    }
}

// ---------------------------------------------------------------------------
// Sparse attention v9: 1 block = 4 waves per query, 8 neighbor streams,
// half-wave-coalesced KV loads, NO max-tracking: scores are O(1)-scaled
// (q,k ~ N(0,1)), so e^s is safely inside fp32 range and softmax is
// shift-invariant. l += e^s ; o[i] += e^s * v[i]. The only cross-iteration
// dependencies are independent FMA accumulates; exp is off the critical
// path. All merges are plain adds. lane = p*32 + h*4 + s; score restored
// across the 4 s-lanes via shfl_xor(1)+shfl_xor(2).
// ---------------------------------------------------------------------------
__global__ __launch_bounds__(256) void sparse_attn9(const _Float16* __restrict__ Qh,
                                                    const _Float16* __restrict__ KV,
                                                    const ushort_t* __restrict__ nbr,
                                                    const int* __restrict__ cnt,
                                                    _Float16* __restrict__ Ob) {
    __shared__ float sm[4][32][12];
    const int q    = blockIdx.x;
    const int t    = threadIdx.x;
    const int wave = t >> 6;
    const int lane = t & 63;
    const int p    = lane >> 5;
    const int h    = (lane >> 2) & 7;
    const int s    = lane & 3;

    // 8-dim q slice for (h,s), f16 -> fp32, pre-scaled by 1/sqrt(HD)
    float qv[8];
    {
        half8 qh = *(const half8*)(Qh + (size_t)q * FDIM + h * HD + s * 8);
        const float sc = 0.17677669529663687f;
#pragma unroll
        for (int i = 0; i < 8; ++i) qv[i] = (float)qh[i] * sc;
    }

    float o[8];
#pragma unroll
    for (int i = 0; i < 8; ++i) o[i] = 0.f;
    float l = 0.f;

    const int n = cnt[q];
    const ushort_t* nl = nbr + (size_t)q * CAP;
    const int koff = h * HD + s * 8;

    for (int j = 2 * wave + p; j < n; j += 8) {
        const int k = nl[j];
        const _Float16* r = KV + ((size_t)k << 9) + koff;
        half8 k8 = *(const half8*)(r);
        half8 v8 = *(const half8*)(r + 256);

        float part = 0.f;
#pragma unroll
        for (int i = 0; i < 8; ++i)
            part = fmaf(qv[i], (float)k8[i], part);
        // full 32-dim score: reduce across the 4 s-lanes of this head
        part += __shfl_xor(part, 1, 64);
        part += __shfl_xor(part, 2, 64);

        const float pw = __expf(part);
        l += pw;
#pragma unroll
        for (int i = 0; i < 8; ++i)
            o[i] = fmaf(pw, (float)v8[i], o[i]);
    }

    // merge the two 32-lane halves (plain sums)
    l += __shfl_xor(l, 32, 64);
#pragma unroll
    for (int i = 0; i < 8; ++i) o[i] += __shfl_xor(o[i], 32, 64);

    if (lane < 32) {  // lane == h*4+s
        float* dst = &sm[wave][lane][0];
        *(float4*)(dst)     = (float4){o[0], o[1], o[2], o[3]};
        *(float4*)(dst + 4) = (float4){o[4], o[5], o[6], o[7]};
        dst[8] = l;
    }
    __syncthreads();

    if (t < 32) {  // t == h*4+s ; output offset = 8*t
        float4 x0 = *(const float4*)&sm[0][t][0];
        float4 x1 = *(const float4*)&sm[0][t][4];
        float O[8] = {x0.x, x0.y, x0.z, x0.w, x1.x, x1.y, x1.z, x1.w};
        float L = sm[0][t][8];
#pragma unroll
        for (int w = 1; w < 4; ++w) {
            float4 y0 = *(const float4*)&sm[w][t][0];
            float4 y1 = *(const float4*)&sm[w][t][4];
            L += sm[w][t][8];
            O[0] += y0.x; O[1] += y0.y; O[2] += y0.z; O[3] += y0.w;
            O[4] += y1.x; O[5] += y1.y; O[6] += y1.z; O[7] += y1.w;
        }
        const float inv = 1.0f / L;  // n==0 -> L==0 -> inf -> NaN, matches ref
        half8 ho;
#pragma unroll
        for (int i = 0; i < 8; ++i) ho[i] = (_Float16)(O[i] * inv);
        *(half8*)(Ob + (size_t)q * FDIM + t * 8) = ho;
    }
}

// ---------------------------------------------------------------------------
extern "C" void kernel_launch(void* const* d_in, const int* in_sizes, int n_in,
                              void* d_out, int out_size, void* d_ws, size_t ws_size,
                              hipStream_t stream) {
    const float* cur_feats   = (const float*)d_in[0];
    const float* hist_feats  = (const float*)d_in[1];
    const float* cur_coords  = (const float*)d_in[2];
    const float* hist_coords = (const float*)d_in[3];
    const float* bq = (const float*)d_in[5];
    const float* bk = (const float*)d_in[7];
    const float* bv = (const float*)d_in[9];
    const float* bo = (const float*)d_in[11];
    float* out = (float*)d_out;

    char* w = (char*)d_ws;
    _Float16*  Qh   = (_Float16*)(w);                      // 4096 x 256 f16 = 2 MiB
    _Float16*  KV   = (_Float16*)(w + (4 << 20));          // 4096 x 512 f16 = 4 MiB
    ushort_t*  nbr  = (ushort_t*)(w + (8 << 20));          // 4 MiB
    int*       cnt  = (int*)(w + (12 << 20));              // 16 KiB
    _Float16*  Ob   = (_Float16*)(w + (12 << 20) + (64 << 10));  // 2 MiB
    _Float16*  cb   = (_Float16*)(w + (15 << 20));         // cast buffer ~4.5 MiB

    prep<<<2048, 256, 0, stream>>>(cur_feats, hist_feats,
                                   (const float*)d_in[4], (const float*)d_in[6],
                                   (const float*)d_in[8], (const float*)d_in[10], cb,
                                   cur_coords, hist_coords, nbr, cnt);

    qkv_mfma<<<dim3(4, 64, 3), 256, 0, stream>>>(cb, bq, bk, bv, Qh, KV);

    sparse_attn9<<<NQ, 256, 0, stream>>>(Qh, KV, nbr, cnt, Ob);

    o_mfma<<<dim3(4, 64), 256, 0, stream>>>(Ob, cb + CB_WO, bo, out);
}